// Round 1
// baseline (130.987 us; speedup 1.0000x reference)
//
#include <hip/hip_runtime.h>

#define BB    4
#define TE    1024
#define TD    512
#define HH    128
#define DTILE 4
#define TTILE 64
#define ESTR  (TE + 8)              // e_s row stride: breaks d-bank aliasing
#define LOG2E 1.4426950408889634f

typedef float f32x2 __attribute__((ext_vector_type(2)));

__device__ __forceinline__ f32x2 pk_fma(f32x2 a, f32x2 b, f32x2 c) {
    return __builtin_elementwise_fma(a, b, c);
}

// Accurate-enough tanh for the proj epilogue (786K elems, off the hot path).
__device__ __forceinline__ float tanh_eval(float x) {
    float e = __builtin_amdgcn_exp2f(2.0f * LOG2E * x);
    return 1.0f - 2.0f * __builtin_amdgcn_rcpf(e + 1.0f);
}

// ---------------------------------------------------------------------------
// Kernel 1: skinny projections (M=6144, N=128, K=128) with tanh epilogue
// (A = tanh(enc@W), B = tanh(dec@U)) so the energy kernel can use the
// tanh addition theorem.
//
// R13 rewrite: the old version ran 192 blocks x 256 thr (0.75 blocks/CU,
// 1 wave/SIMD) with 8 barriers and exposed HBM latency per phase ->
// latency-bound at ~3.5 TFLOPS. New structure: 384 blocks x 512 thr
// (3 waves/SIMD), X row-tile staged once in LDS (1 barrier total), W rows
// streamed from L1/L2 (64 KB, shared by all 8 waves in lockstep), packed
// FMAs with split accumulators, 16 loads in flight via unroll.
// ---------------------------------------------------------------------------
__global__ __launch_bounds__(512) void proj_gemm(
    const float* __restrict__ enc, const float* __restrict__ dec,
    const float* __restrict__ Wa,  const float* __restrict__ Ua,
    float* __restrict__ out)
{
    __shared__ float Xs[16 * HH];   // 8 KB, fully aligned, conflict-free

    const int tid = threadIdx.x;
    const int r0  = blockIdx.x * 16;

    const float* X; const float* W; int rX0;
    if (r0 < BB * TE) { X = enc; W = Wa; rX0 = r0; }
    else              { X = dec; W = Ua; rX0 = r0 - BB * TE; }

    // Stage the 16x128 X tile: one float4 per thread, coalesced.
    {
        const int r = tid >> 5, c = tid & 31;
        *(float4*)&Xs[r * HH + c * 4] =
            *(const float4*)&X[(size_t)(rX0 + r) * HH + c * 4];
    }
    __syncthreads();

    const int rr = tid >> 5;        // 0..15 : output row within tile
    const int c4 = tid & 31;        // 0..31 : output float4 column group

    // Split accumulators (even/odd k) to break the pk_fma dependency chain.
    f32x2 aL0 = {0.f, 0.f}, aH0 = {0.f, 0.f};
    f32x2 aL1 = {0.f, 0.f}, aH1 = {0.f, 0.f};

    const float* Wc   = W + c4 * 4;
    const float* xrow = &Xs[rr * HH];

    #pragma unroll 4
    for (int k = 0; k < HH; k += 4) {
        float4 w0 = *(const float4*)&Wc[(k + 0) * HH];
        float4 w1 = *(const float4*)&Wc[(k + 1) * HH];
        float4 w2 = *(const float4*)&Wc[(k + 2) * HH];
        float4 w3 = *(const float4*)&Wc[(k + 3) * HH];
        float4 xv = *(const float4*)&xrow[k];   // ds_read_b128 broadcast

        aL0 = pk_fma((f32x2){xv.x, xv.x}, (f32x2){w0.x, w0.y}, aL0);
        aH0 = pk_fma((f32x2){xv.x, xv.x}, (f32x2){w0.z, w0.w}, aH0);
        aL1 = pk_fma((f32x2){xv.y, xv.y}, (f32x2){w1.x, w1.y}, aL1);
        aH1 = pk_fma((f32x2){xv.y, xv.y}, (f32x2){w1.z, w1.w}, aH1);
        aL0 = pk_fma((f32x2){xv.z, xv.z}, (f32x2){w2.x, w2.y}, aL0);
        aH0 = pk_fma((f32x2){xv.z, xv.z}, (f32x2){w2.z, w2.w}, aH0);
        aL1 = pk_fma((f32x2){xv.w, xv.w}, (f32x2){w3.x, w3.y}, aL1);
        aH1 = pk_fma((f32x2){xv.w, xv.w}, (f32x2){w3.z, w3.w}, aH1);
    }

    f32x2 aL = aL0 + aL1;
    f32x2 aH = aH0 + aH1;

    float4 o;
    o.x = tanh_eval(aL.x); o.y = tanh_eval(aL.y);
    o.z = tanh_eval(aH.x); o.w = tanh_eval(aH.y);
    *(float4*)&out[(size_t)(r0 + rr) * HH + c4 * 4] = o;
}

// ---------------------------------------------------------------------------
// Kernel 2: fused energies -> softmax -> context. R12 structure (depth-2,
// ESTR pad) with PACKED-F32 math: phase-1 fraction tree and phase-3 FMAs
// rewritten on f32x2 so the backend emits v_pk_fma_f32 (2 elems/slot).
// (Unchanged this round to isolate the proj_gemm delta.)
// ---------------------------------------------------------------------------
__global__ __launch_bounds__(512, 4) void attn_fused(
    const float* __restrict__ enc,    // [B, TE, H] raw
    const float* __restrict__ ta,     // [B*TE, H]  = tanh(W_s)
    const float* __restrict__ tb,     // [B*TD, H]  = tanh(U_h)
    const float* __restrict__ Va,     // [H]
    float* __restrict__ c_out,        // [B, TD, H]
    float* __restrict__ e_out)        // [B, TD, TE]
{
    __shared__ float e_s[DTILE * ESTR];     // 16.1 KB
    __shared__ float c_red[8 * DTILE * HH]; // 16 KB

    const int tid = threadIdx.x;
    const int l   = tid & 63;
    const int w   = tid >> 6;            // 0..7 (row-octet owner)
    const int b   = blockIdx.x >> 7;
    const int d0  = (blockIdx.x & 127) * DTILE;

    // ---------------- Phase 1: energies ----------------
    {
        const int g  = l >> 3;           // group 0..7
        const int hl = l & 7;            // h-chunk offset within group
        const int dl = g & 3;            // this group's decoder step
        const int rh = g >> 2;           // row parity

        // Lane constants as f32x2: B, Bp = v*B, v (24 f32x2 = 48 regs).
        f32x2 Bl[4], Bh[4], Pl[4], Ph[4], Vl[4], Vh[4];
        #pragma unroll
        for (int j = 0; j < 4; ++j) {
            float4 vv = *(const float4*)&Va[(j * 8 + hl) * 4];
            float4 bb = *(const float4*)&tb[((size_t)b * TD + d0 + dl) * HH + (j * 8 + hl) * 4];
            Vl[j] = (f32x2){vv.x, vv.y};  Vh[j] = (f32x2){vv.z, vv.w};
            Bl[j] = (f32x2){bb.x, bb.y};  Bh[j] = (f32x2){bb.z, bb.w};
            Pl[j] = Vl[j] * Bl[j];        Ph[j] = Vh[j] * Bh[j];
        }

        const float* ta_b = ta + (size_t)b * TE * HH;

        // Wave w covers rows {(i>>2)*64 + w*8 + (i&3)*2 + rh}, i = 0..63.
        auto rowOf = [&](int i) {
            return ((i >> 2) << 6) + w * 8 + ((i & 3) << 1) + rh;
        };

        float4 A0[4], A1[4];
        auto loadA = [&](int i, float4 (&A)[4]) {
            const float* base = ta_b + (size_t)rowOf(i) * HH;
            #pragma unroll
            for (int j = 0; j < 4; ++j)
                A[j] = *(const float4*)&base[(j * 8 + hl) * 4];
        };

        auto p1c = [&](int i, float4 (&A)[4]) {
            const f32x2 one2 = {1.0f, 1.0f};
            f32x2 n2[8], d2[8];
            #pragma unroll
            for (int j = 0; j < 4; ++j) {
                f32x2 Al = (f32x2){A[j].x, A[j].y};
                f32x2 Ah = (f32x2){A[j].z, A[j].w};
                n2[2 * j]     = pk_fma(Vl[j], Al, Pl[j]);
                n2[2 * j + 1] = pk_fma(Vh[j], Ah, Ph[j]);
                d2[2 * j]     = pk_fma(Al, Bl[j], one2);
                d2[2 * j + 1] = pk_fma(Ah, Bh[j], one2);
            }
            // Vertical packed fraction-combine tree: 8 -> 4 -> 2 -> 1.
            #pragma unroll
            for (int s = 4; s >= 1; s >>= 1) {
                #pragma unroll
                for (int k = 0; k < s; ++k) {
                    n2[k] = pk_fma(n2[2 * k], d2[2 * k + 1], n2[2 * k + 1] * d2[2 * k]);
                    d2[k] = d2[2 * k] * d2[2 * k + 1];
                }
            }
            // Horizontal: combine the two sub-fractions in .x/.y.
            float num = n2[0].x * d2[0].y + n2[0].y * d2[0].x;
            float den = d2[0].x * d2[0].y;
            float e = num * __builtin_amdgcn_rcpf(den);
            e += __shfl_xor(e, 1);
            e += __shfl_xor(e, 2);
            e += __shfl_xor(e, 4);
            if (hl == 0) e_s[dl * ESTR + rowOf(i)] = e;
        };

        loadA(0, A0);
        #pragma unroll 1
        for (int i = 0; i < 62; i += 2) {
            loadA(i + 1, A1);
            p1c(i, A0);
            loadA(i + 2, A0);
            p1c(i + 1, A1);
        }
        loadA(63, A1);
        p1c(62, A0);
        p1c(63, A1);
    }
    __syncthreads();   // all waves' raw energies visible

    // ---------------- Phase 2: softmax (d = w&3, two waves split halves) ----
    {
        const int d2 = w & 3, hf = w >> 2;
        float ev[16];
        float m = -3.0e38f;
        #pragma unroll
        for (int i = 0; i < 16; ++i) {
            ev[i] = e_s[d2 * ESTR + i * 64 + l];
            m = fmaxf(m, ev[i]);
        }
        #pragma unroll
        for (int off = 32; off; off >>= 1) m = fmaxf(m, __shfl_xor(m, off));
        float s = 0.f;
        #pragma unroll
        for (int i = 0; i < 16; ++i) {
            ev[i] = __builtin_amdgcn_exp2f((ev[i] - m) * LOG2E);
            s += ev[i];
        }
        #pragma unroll
        for (int off = 32; off; off >>= 1) s += __shfl_xor(s, off);
        float inv = __builtin_amdgcn_rcpf(s);

        __syncthreads();   // all raw-energy reads done before overwrite
        float* eo = e_out + ((size_t)b * TD + d0 + d2) * TE;
        #pragma unroll
        for (int i = 0; i < 8; ++i) {
            int ii = hf * 8 + i;
            float p = ev[ii] * inv;
            e_s[d2 * ESTR + ii * 64 + l] = p;
            eo[ii * 64 + l] = p;
        }
        __syncthreads();   // normalized p visible to all waves
    }

    // ---------------- Phase 3: context (packed FMAs, register pingpong) -----
    const int h4 = l & 31, tsub = l >> 5;
    f32x2 accL[DTILE], accH[DTILE];
    #pragma unroll
    for (int d = 0; d < DTILE; ++d) {
        accL[d] = (f32x2){0.f, 0.f};
        accH[d] = (f32x2){0.f, 0.f};
    }

    {
        const float* enc_w = enc + ((size_t)b * TE + w * 8) * HH;
        float4 X0[4], X1[4];

        auto loadX = [&](int tt, float4 (&X)[4]) {
            const float* base = enc_w + (size_t)tt * TTILE * HH;
            #pragma unroll
            for (int k = 0; k < 4; ++k)
                X[k] = *(const float4*)&base[(tsub * 4 + k) * HH + h4 * 4];
        };

        auto p3c = [&](int tt, float4 (&X)[4]) {
            float4 ep[DTILE];
            #pragma unroll
            for (int d = 0; d < DTILE; ++d)
                ep[d] = *(const float4*)&e_s[d * ESTR + tt * TTILE + w * 8 + tsub * 4];
            #pragma unroll
            for (int k = 0; k < 4; ++k) {
                f32x2 xL = (f32x2){X[k].x, X[k].y};
                f32x2 xH = (f32x2){X[k].z, X[k].w};
                #pragma unroll
                for (int d = 0; d < DTILE; ++d) {
                    float p = k == 0 ? ep[d].x : k == 1 ? ep[d].y
                            : k == 2 ? ep[d].z : ep[d].w;
                    f32x2 pv = (f32x2){p, p};
                    accL[d] = pk_fma(pv, xL, accL[d]);
                    accH[d] = pk_fma(pv, xH, accH[d]);
                }
            }
        };

        loadX(0, X0);
        #pragma unroll 1
        for (int tt = 0; tt < 14; tt += 2) {
            loadX(tt + 1, X1);
            p3c(tt, X0);
            loadX(tt + 2, X0);
            p3c(tt + 1, X1);
        }
        loadX(15, X1);
        p3c(14, X0);
        p3c(15, X1);
    }

    // Combine tsub halves; park per-wave partials; tree-reduce across waves.
    float4 acc4[DTILE];
    #pragma unroll
    for (int d = 0; d < DTILE; ++d)
        acc4[d] = make_float4(accL[d].x, accL[d].y, accH[d].x, accH[d].y);
    #pragma unroll
    for (int d = 0; d < DTILE; ++d) {
        acc4[d].x += __shfl_xor(acc4[d].x, 32);
        acc4[d].y += __shfl_xor(acc4[d].y, 32);
        acc4[d].z += __shfl_xor(acc4[d].z, 32);
        acc4[d].w += __shfl_xor(acc4[d].w, 32);
    }
    if (tsub == 0) {
        #pragma unroll
        for (int d = 0; d < DTILE; ++d)
            *(float4*)&c_red[(w * DTILE + d) * HH + h4 * 4] = acc4[d];
    }
    __syncthreads();

    if (w < DTILE && l < 32) {
        float4 o = make_float4(0.f, 0.f, 0.f, 0.f);
        #pragma unroll
        for (int ww = 0; ww < 8; ++ww) {
            float4 p = *(const float4*)&c_red[(ww * DTILE + w) * HH + l * 4];
            o.x += p.x; o.y += p.y; o.z += p.z; o.w += p.w;
        }
        *(float4*)&c_out[((size_t)b * TD + d0 + w) * HH + l * 4] = o;
    }
}

// ---------------------------------------------------------------------------
extern "C" void kernel_launch(void* const* d_in, const int* in_sizes, int n_in,
                              void* d_out, int out_size, void* d_ws, size_t ws_size,
                              hipStream_t stream) {
    (void)in_sizes; (void)n_in; (void)out_size; (void)ws_size;

    const float* enc = (const float*)d_in[0];
    const float* dec = (const float*)d_in[1];
    const float* Wa  = (const float*)d_in[2];
    const float* Ua  = (const float*)d_in[3];
    const float* Va  = (const float*)d_in[4];

    float* c_out = (float*)d_out;
    float* e_out = (float*)d_out + BB * TD * HH;

    float* proj = (float*)d_ws;
    float* ta_p = proj;                  // tanh(W_s): [B*TE, H]
    float* tb_p = proj + BB * TE * HH;   // tanh(U_h): [B*TD, H]

    proj_gemm<<<384, 512, 0, stream>>>(enc, dec, Wa, Ua, proj);
    attn_fused<<<(BB * TD) / DTILE, 512, 0, stream>>>(enc, ta_p, tb_p, Va, c_out, e_out);
}

// Round 4
// 120.763 us; speedup vs baseline: 1.0847x; 1.0847x over previous
//
#include <hip/hip_runtime.h>

#define BB    4
#define TE    1024
#define TD    512
#define HH    128
#define DTILE 4
#define TTILE 64
#define ESTR  (TE + 8)              // e_s row stride: breaks d-bank aliasing
#define LOG2E 1.4426950408889634f

typedef float f32x2 __attribute__((ext_vector_type(2)));

__device__ __forceinline__ f32x2 pk_fma(f32x2 a, f32x2 b, f32x2 c) {
    return __builtin_elementwise_fma(a, b, c);
}

// Accurate-enough tanh for the proj epilogue (786K elems, off the hot path).
__device__ __forceinline__ float tanh_eval(float x) {
    float e = __builtin_amdgcn_exp2f(2.0f * LOG2E * x);
    return 1.0f - 2.0f * __builtin_amdgcn_rcpf(e + 1.0f);
}

// ---------------------------------------------------------------------------
// Kernel 1: skinny projections (M=6144, N=128, K=128) with tanh epilogue.
//
// R14 (2nd resubmit after back-to-back GPU-acquisition timeouts): R13
// streamed W from global in lockstep across all waves -> ~100% L1 miss
// (64KB W > 32KB L1, cyclic sweep) + L2 single-slice hotspot (every CU
// requesting the SAME line every cycle) -> ~200MB at degraded BW ~= 70us.
// Fix: stage the full 64KB W into LDS once per block (coalesced over
// DISTINCT lines -> no slice hotspot; 24MB total one-shot), then the k-loop
// reads W via conflict-free ds_read_b128 (256 words/wave spread exactly
// 8/bank). LDS 72KB -> 2 blocks/CU, 16 waves/CU. One barrier total.
// ---------------------------------------------------------------------------
__global__ __launch_bounds__(512, 2) void proj_gemm(
    const float* __restrict__ enc, const float* __restrict__ dec,
    const float* __restrict__ Wa,  const float* __restrict__ Ua,
    float* __restrict__ out)
{
    __shared__ float Ws[HH * HH];   // 64 KB: W[k][c], row-major
    __shared__ float Xs[16 * HH];   // 8 KB

    const int tid = threadIdx.x;
    const int r0  = blockIdx.x * 16;

    const float* X; const float* W; int rX0;
    if (r0 < BB * TE) { X = enc; W = Wa; rX0 = r0; }
    else              { X = dec; W = Ua; rX0 = r0 - BB * TE; }

    // Stage W: 16384 floats / 512 thr = 8 float4 per thread, fully coalesced,
    // each wave-instr covers 1KB of distinct lines (no broadcast hotspot).
    #pragma unroll
    for (int i = 0; i < 8; ++i)
        *(float4*)&Ws[i * 2048 + tid * 4] =
            *(const float4*)&W[i * 2048 + tid * 4];

    // Stage the 16x128 X tile: one float4 per thread, coalesced.
    {
        const int r = tid >> 5, c = tid & 31;
        *(float4*)&Xs[r * HH + c * 4] =
            *(const float4*)&X[(size_t)(rX0 + r) * HH + c * 4];
    }
    __syncthreads();

    const int rr = tid >> 5;        // 0..15 : output row within tile
    const int c4 = tid & 31;        // 0..31 : output float4 column group

    // Split accumulators (even/odd k) to break the pk_fma dependency chain.
    f32x2 aL0 = {0.f, 0.f}, aH0 = {0.f, 0.f};
    f32x2 aL1 = {0.f, 0.f}, aH1 = {0.f, 0.f};

    const float* wc   = &Ws[c4 * 4];    // ds base; k*512B fits 16-bit offset
    const float* xrow = &Xs[rr * HH];

    #pragma unroll 4
    for (int k = 0; k < HH; k += 4) {
        float4 w0 = *(const float4*)&wc[(k + 0) * HH];
        float4 w1 = *(const float4*)&wc[(k + 1) * HH];
        float4 w2 = *(const float4*)&wc[(k + 2) * HH];
        float4 w3 = *(const float4*)&wc[(k + 3) * HH];
        float4 xv = *(const float4*)&xrow[k];   // broadcast ds_read_b128

        aL0 = pk_fma((f32x2){xv.x, xv.x}, (f32x2){w0.x, w0.y}, aL0);
        aH0 = pk_fma((f32x2){xv.x, xv.x}, (f32x2){w0.z, w0.w}, aH0);
        aL1 = pk_fma((f32x2){xv.y, xv.y}, (f32x2){w1.x, w1.y}, aL1);
        aH1 = pk_fma((f32x2){xv.y, xv.y}, (f32x2){w1.z, w1.w}, aH1);
        aL0 = pk_fma((f32x2){xv.z, xv.z}, (f32x2){w2.x, w2.y}, aL0);
        aH0 = pk_fma((f32x2){xv.z, xv.z}, (f32x2){w2.z, w2.w}, aH0);
        aL1 = pk_fma((f32x2){xv.w, xv.w}, (f32x2){w3.x, w3.y}, aL1);
        aH1 = pk_fma((f32x2){xv.w, xv.w}, (f32x2){w3.z, w3.w}, aH1);
    }

    f32x2 aL = aL0 + aL1;
    f32x2 aH = aH0 + aH1;

    float4 o;
    o.x = tanh_eval(aL.x); o.y = tanh_eval(aL.y);
    o.z = tanh_eval(aH.x); o.w = tanh_eval(aH.y);
    *(float4*)&out[(size_t)(r0 + rr) * HH + c4 * 4] = o;
}

// ---------------------------------------------------------------------------
// Kernel 2: fused energies -> softmax -> context. R12 structure (depth-2,
// ESTR pad) with PACKED-F32 math: phase-1 fraction tree and phase-3 FMAs
// rewritten on f32x2 so the backend emits v_pk_fma_f32 (2 elems/slot).
// (Unchanged this round to isolate the proj_gemm delta.)
// ---------------------------------------------------------------------------
__global__ __launch_bounds__(512, 4) void attn_fused(
    const float* __restrict__ enc,    // [B, TE, H] raw
    const float* __restrict__ ta,     // [B*TE, H]  = tanh(W_s)
    const float* __restrict__ tb,     // [B*TD, H]  = tanh(U_h)
    const float* __restrict__ Va,     // [H]
    float* __restrict__ c_out,        // [B, TD, H]
    float* __restrict__ e_out)        // [B, TD, TE]
{
    __shared__ float e_s[DTILE * ESTR];     // 16.1 KB
    __shared__ float c_red[8 * DTILE * HH]; // 16 KB

    const int tid = threadIdx.x;
    const int l   = tid & 63;
    const int w   = tid >> 6;            // 0..7 (row-octet owner)
    const int b   = blockIdx.x >> 7;
    const int d0  = (blockIdx.x & 127) * DTILE;

    // ---------------- Phase 1: energies ----------------
    {
        const int g  = l >> 3;           // group 0..7
        const int hl = l & 7;            // h-chunk offset within group
        const int dl = g & 3;            // this group's decoder step
        const int rh = g >> 2;           // row parity

        // Lane constants as f32x2: B, Bp = v*B, v (24 f32x2 = 48 regs).
        f32x2 Bl[4], Bh[4], Pl[4], Ph[4], Vl[4], Vh[4];
        #pragma unroll
        for (int j = 0; j < 4; ++j) {
            float4 vv = *(const float4*)&Va[(j * 8 + hl) * 4];
            float4 bb = *(const float4*)&tb[((size_t)b * TD + d0 + dl) * HH + (j * 8 + hl) * 4];
            Vl[j] = (f32x2){vv.x, vv.y};  Vh[j] = (f32x2){vv.z, vv.w};
            Bl[j] = (f32x2){bb.x, bb.y};  Bh[j] = (f32x2){bb.z, bb.w};
            Pl[j] = Vl[j] * Bl[j];        Ph[j] = Vh[j] * Bh[j];
        }

        const float* ta_b = ta + (size_t)b * TE * HH;

        // Wave w covers rows {(i>>2)*64 + w*8 + (i&3)*2 + rh}, i = 0..63.
        auto rowOf = [&](int i) {
            return ((i >> 2) << 6) + w * 8 + ((i & 3) << 1) + rh;
        };

        float4 A0[4], A1[4];
        auto loadA = [&](int i, float4 (&A)[4]) {
            const float* base = ta_b + (size_t)rowOf(i) * HH;
            #pragma unroll
            for (int j = 0; j < 4; ++j)
                A[j] = *(const float4*)&base[(j * 8 + hl) * 4];
        };

        auto p1c = [&](int i, float4 (&A)[4]) {
            const f32x2 one2 = {1.0f, 1.0f};
            f32x2 n2[8], d2[8];
            #pragma unroll
            for (int j = 0; j < 4; ++j) {
                f32x2 Al = (f32x2){A[j].x, A[j].y};
                f32x2 Ah = (f32x2){A[j].z, A[j].w};
                n2[2 * j]     = pk_fma(Vl[j], Al, Pl[j]);
                n2[2 * j + 1] = pk_fma(Vh[j], Ah, Ph[j]);
                d2[2 * j]     = pk_fma(Al, Bl[j], one2);
                d2[2 * j + 1] = pk_fma(Ah, Bh[j], one2);
            }
            // Vertical packed fraction-combine tree: 8 -> 4 -> 2 -> 1.
            #pragma unroll
            for (int s = 4; s >= 1; s >>= 1) {
                #pragma unroll
                for (int k = 0; k < s; ++k) {
                    n2[k] = pk_fma(n2[2 * k], d2[2 * k + 1], n2[2 * k + 1] * d2[2 * k]);
                    d2[k] = d2[2 * k] * d2[2 * k + 1];
                }
            }
            // Horizontal: combine the two sub-fractions in .x/.y.
            float num = n2[0].x * d2[0].y + n2[0].y * d2[0].x;
            float den = d2[0].x * d2[0].y;
            float e = num * __builtin_amdgcn_rcpf(den);
            e += __shfl_xor(e, 1);
            e += __shfl_xor(e, 2);
            e += __shfl_xor(e, 4);
            if (hl == 0) e_s[dl * ESTR + rowOf(i)] = e;
        };

        loadA(0, A0);
        #pragma unroll 1
        for (int i = 0; i < 62; i += 2) {
            loadA(i + 1, A1);
            p1c(i, A0);
            loadA(i + 2, A0);
            p1c(i + 1, A1);
        }
        loadA(63, A1);
        p1c(62, A0);
        p1c(63, A1);
    }
    __syncthreads();   // all waves' raw energies visible

    // ---------------- Phase 2: softmax (d = w&3, two waves split halves) ----
    {
        const int d2 = w & 3, hf = w >> 2;
        float ev[16];
        float m = -3.0e38f;
        #pragma unroll
        for (int i = 0; i < 16; ++i) {
            ev[i] = e_s[d2 * ESTR + i * 64 + l];
            m = fmaxf(m, ev[i]);
        }
        #pragma unroll
        for (int off = 32; off; off >>= 1) m = fmaxf(m, __shfl_xor(m, off));
        float s = 0.f;
        #pragma unroll
        for (int i = 0; i < 16; ++i) {
            ev[i] = __builtin_amdgcn_exp2f((ev[i] - m) * LOG2E);
            s += ev[i];
        }
        #pragma unroll
        for (int off = 32; off; off >>= 1) s += __shfl_xor(s, off);
        float inv = __builtin_amdgcn_rcpf(s);

        __syncthreads();   // all raw-energy reads done before overwrite
        float* eo = e_out + ((size_t)b * TD + d0 + d2) * TE;
        #pragma unroll
        for (int i = 0; i < 8; ++i) {
            int ii = hf * 8 + i;
            float p = ev[ii] * inv;
            e_s[d2 * ESTR + ii * 64 + l] = p;
            eo[ii * 64 + l] = p;
        }
        __syncthreads();   // normalized p visible to all waves
    }

    // ---------------- Phase 3: context (packed FMAs, register pingpong) -----
    const int h4 = l & 31, tsub = l >> 5;
    f32x2 accL[DTILE], accH[DTILE];
    #pragma unroll
    for (int d = 0; d < DTILE; ++d) {
        accL[d] = (f32x2){0.f, 0.f};
        accH[d] = (f32x2){0.f, 0.f};
    }

    {
        const float* enc_w = enc + ((size_t)b * TE + w * 8) * HH;
        float4 X0[4], X1[4];

        auto loadX = [&](int tt, float4 (&X)[4]) {
            const float* base = enc_w + (size_t)tt * TTILE * HH;
            #pragma unroll
            for (int k = 0; k < 4; ++k)
                X[k] = *(const float4*)&base[(tsub * 4 + k) * HH + h4 * 4];
        };

        auto p3c = [&](int tt, float4 (&X)[4]) {
            float4 ep[DTILE];
            #pragma unroll
            for (int d = 0; d < DTILE; ++d)
                ep[d] = *(const float4*)&e_s[d * ESTR + tt * TTILE + w * 8 + tsub * 4];
            #pragma unroll
            for (int k = 0; k < 4; ++k) {
                f32x2 xL = (f32x2){X[k].x, X[k].y};
                f32x2 xH = (f32x2){X[k].z, X[k].w};
                #pragma unroll
                for (int d = 0; d < DTILE; ++d) {
                    float p = k == 0 ? ep[d].x : k == 1 ? ep[d].y
                            : k == 2 ? ep[d].z : ep[d].w;
                    f32x2 pv = (f32x2){p, p};
                    accL[d] = pk_fma(pv, xL, accL[d]);
                    accH[d] = pk_fma(pv, xH, accH[d]);
                }
            }
        };

        loadX(0, X0);
        #pragma unroll 1
        for (int tt = 0; tt < 14; tt += 2) {
            loadX(tt + 1, X1);
            p3c(tt, X0);
            loadX(tt + 2, X0);
            p3c(tt + 1, X1);
        }
        loadX(15, X1);
        p3c(14, X0);
        p3c(15, X1);
    }

    // Combine tsub halves; park per-wave partials; tree-reduce across waves.
    float4 acc4[DTILE];
    #pragma unroll
    for (int d = 0; d < DTILE; ++d)
        acc4[d] = make_float4(accL[d].x, accL[d].y, accH[d].x, accH[d].y);
    #pragma unroll
    for (int d = 0; d < DTILE; ++d) {
        acc4[d].x += __shfl_xor(acc4[d].x, 32);
        acc4[d].y += __shfl_xor(acc4[d].y, 32);
        acc4[d].z += __shfl_xor(acc4[d].z, 32);
        acc4[d].w += __shfl_xor(acc4[d].w, 32);
    }
    if (tsub == 0) {
        #pragma unroll
        for (int d = 0; d < DTILE; ++d)
            *(float4*)&c_red[(w * DTILE + d) * HH + h4 * 4] = acc4[d];
    }
    __syncthreads();

    if (w < DTILE && l < 32) {
        float4 o = make_float4(0.f, 0.f, 0.f, 0.f);
        #pragma unroll
        for (int ww = 0; ww < 8; ++ww) {
            float4 p = *(const float4*)&c_red[(ww * DTILE + w) * HH + l * 4];
            o.x += p.x; o.y += p.y; o.z += p.z; o.w += p.w;
        }
        *(float4*)&c_out[((size_t)b * TD + d0 + w) * HH + l * 4] = o;
    }
}

// ---------------------------------------------------------------------------
extern "C" void kernel_launch(void* const* d_in, const int* in_sizes, int n_in,
                              void* d_out, int out_size, void* d_ws, size_t ws_size,
                              hipStream_t stream) {
    (void)in_sizes; (void)n_in; (void)out_size; (void)ws_size;

    const float* enc = (const float*)d_in[0];
    const float* dec = (const float*)d_in[1];
    const float* Wa  = (const float*)d_in[2];
    const float* Ua  = (const float*)d_in[3];
    const float* Va  = (const float*)d_in[4];

    float* c_out = (float*)d_out;
    float* e_out = (float*)d_out + BB * TD * HH;

    float* proj = (float*)d_ws;
    float* ta_p = proj;                  // tanh(W_s): [B*TE, H]
    float* tb_p = proj + BB * TE * HH;   // tanh(U_h): [B*TD, H]

    proj_gemm<<<384, 512, 0, stream>>>(enc, dec, Wa, Ua, proj);
    attn_fused<<<(BB * TD) / DTILE, 512, 0, stream>>>(enc, ta_p, tb_p, Va, c_out, e_out);
}